// Round 5
// baseline (685.250 us; speedup 1.0000x reference)
//
#include <hip/hip_runtime.h>
#include <math.h>

#define BB 8
#define NN 50000
#define FF 256
#define KK 1024
#define CHUNK 400
#define NCHUNK 125   // 125 * 400 = 50000 exactly
#define NIT (CHUNK / 16)
#define CAPA 4096
#define RBLK 16      // rank blocks per batch
#define SB   32      // streaming blocks per batch for hist2/collect

// ---------- helpers ----------
__device__ __forceinline__ unsigned long long key64(double x) {
    unsigned long long u = (unsigned long long)__double_as_longlong(x);
    u ^= (u & 0x8000000000000000ull) ? 0xFFFFFFFFFFFFFFFFull : 0x8000000000000000ull;
    return u;
}
__device__ __forceinline__ double key_to_double(unsigned long long k) {
    unsigned long long u = (k & 0x8000000000000000ull) ? (k ^ 0x8000000000000000ull) : ~k;
    return __longlong_as_double((long long)u);
}

// ---------- zero hist1 + hist2 + ccnt (ws is poisoned 0xAA) ----------
__global__ __launch_bounds__(1024) void zero_kernel(unsigned int* __restrict__ p, int n) {
    int i = blockIdx.x * 1024 + threadIdx.x;
    if (i < n) p[i] = 0u;
}

// ---------- phase 1: scores + fused 11-bit radix histogram ----------
// (HW-verified: 16-lane-group dot, one shared 4-step fp64 butterfly per 4 rows,
// pipelined slab loads; at ~HBM floor for the 410 MB emb stream.)
__global__ __launch_bounds__(256) void score_kernel(const float* __restrict__ emb,
                                                    const float* __restrict__ mask,
                                                    const float* __restrict__ scorer,
                                                    double* __restrict__ scores,
                                                    unsigned int* __restrict__ ghist) {
    const int b    = blockIdx.x / NCHUNK;
    const int c    = blockIdx.x % NCHUNK;
    const int n0   = c * CHUNK;
    const int lane = threadIdx.x & 63;
    const int wave = threadIdx.x >> 6;
    const int s    = lane & 15;
    const int g    = lane >> 4;
    const int r0   = wave * 4 + g;

    __shared__ unsigned int h[2048];
    __shared__ float smask[CHUNK];
    for (int i = threadIdx.x; i < 2048; i += 256) h[i] = 0u;
    for (int i = threadIdx.x; i < CHUNK; i += 256) smask[i] = mask[b * NN + n0 + i];
    __syncthreads();

    double scd[16];
    {
        float4 f0 = ((const float4*)scorer)[s];
        float4 f1 = ((const float4*)scorer)[s + 16];
        float4 f2 = ((const float4*)scorer)[s + 32];
        float4 f3 = ((const float4*)scorer)[s + 48];
        scd[0]  = f0.x; scd[1]  = f0.y; scd[2]  = f0.z; scd[3]  = f0.w;
        scd[4]  = f1.x; scd[5]  = f1.y; scd[6]  = f1.z; scd[7]  = f1.w;
        scd[8]  = f2.x; scd[9]  = f2.y; scd[10] = f2.z; scd[11] = f2.w;
        scd[12] = f3.x; scd[13] = f3.y; scd[14] = f3.z; scd[15] = f3.w;
    }
    double n2 = 0.0;
    #pragma unroll
    for (int e = 0; e < 16; ++e) n2 += scd[e] * scd[e];
    #pragma unroll
    for (int off = 8; off; off >>= 1) n2 += __shfl_xor(n2, off, 64);
    const double inv_norm = 1.0 / sqrt(n2);

    const float* base  = emb + ((long)b * NN + n0) * FF;
    double*      sbase = scores + (long)b * NN + n0;

    auto step = [&](int it, const float4* vv) {
        double d = 0.0;
        #pragma unroll
        for (int i2 = 0; i2 < 4; ++i2) {
            d += (double)vv[i2].x * scd[4 * i2 + 0] + (double)vv[i2].y * scd[4 * i2 + 1] +
                 (double)vv[i2].z * scd[4 * i2 + 2] + (double)vv[i2].w * scd[4 * i2 + 3];
        }
        #pragma unroll
        for (int off = 8; off; off >>= 1) d += __shfl_xor(d, off, 64);
        if (s == 0) {
            const int row = it * 16 + r0;
            double sv = d * inv_norm + (double)smask[row];
            sbase[row] = sv;
            atomicAdd(&h[(unsigned)(key64(sv) >> 53)], 1u);
        }
    };

    const float* rp = base + r0 * FF;
    float4 v[4], w[4];
    #pragma unroll
    for (int i = 0; i < 4; ++i) v[i] = ((const float4*)rp)[s + 16 * i];

    for (int it = 0; it < NIT - 1; ++it) {
        rp += 16 * FF;
        #pragma unroll
        for (int i = 0; i < 4; ++i) w[i] = ((const float4*)rp)[s + 16 * i];
        step(it, v);
        #pragma unroll
        for (int i = 0; i < 4; ++i) v[i] = w[i];
    }
    step(NIT - 1, v);

    __syncthreads();
    unsigned int* gh = ghist + b * 2048;
    for (int i = threadIdx.x; i < 2048; i += 256) {
        unsigned int vv = h[i];
        if (vv) atomicAdd(&gh[i], vv);
    }
}

// ---------- phase 2a: suffix-scan hist1 -> (bin1, need2) ----------
__global__ __launch_bounds__(1024) void scan1_kernel(const unsigned int* __restrict__ ghist,
                                                     int* __restrict__ meta) {
    const int b = blockIdx.x, tid = threadIdx.x;
    __shared__ unsigned int h[2048];
    const int i0 = tid, i1 = tid + 1024;
    h[i0] = ghist[b * 2048 + i0];
    h[i1] = ghist[b * 2048 + i1];
    __syncthreads();
    for (int off = 1; off < 2048; off <<= 1) {
        unsigned a0 = (i0 + off < 2048) ? h[i0 + off] : 0u;
        unsigned a1 = (i1 + off < 2048) ? h[i1 + off] : 0u;
        __syncthreads();
        h[i0] += a0; h[i1] += a1;
        __syncthreads();
    }
    if (h[i0] >= (unsigned)KK && (i0 == 2047 || h[i0 + 1] < (unsigned)KK)) {
        meta[b * 4 + 0] = i0;
        meta[b * 4 + 1] = KK - (int)((i0 == 2047) ? 0u : h[i0 + 1]);
    }
    if (h[i1] >= (unsigned)KK && (i1 == 2047 || h[i1 + 1] < (unsigned)KK)) {
        meta[b * 4 + 0] = i1;
        meta[b * 4 + 1] = KK - (int)((i1 == 2047) ? 0u : h[i1 + 1]);
    }
}

// ---------- phase 2b: chip-parallel hist2 (bits 52..42, restricted to bin1) ----------
__global__ __launch_bounds__(256) void hist2_kernel(const double* __restrict__ scores,
                                                    const int* __restrict__ meta,
                                                    unsigned int* __restrict__ ghist2) {
    const int b = blockIdx.x / SB;
    const int s = blockIdx.x % SB;
    const unsigned long long bin1 = (unsigned long long)meta[b * 4 + 0];
    const double* sc = scores + (long)b * NN;
    unsigned int* h2 = ghist2 + b * 2048;
    for (int i = s * 256 + threadIdx.x; i < NN / 2; i += SB * 256) {
        double2 v = ((const double2*)sc)[i];
        unsigned long long k0 = key64(v.x), k1 = key64(v.y);
        if ((k0 >> 53) == bin1) atomicAdd(&h2[(unsigned)((k0 >> 42) & 2047ull)], 1u);
        if ((k1 >> 53) == bin1) atomicAdd(&h2[(unsigned)((k1 >> 42) & 2047ull)], 1u);
    }
}

// ---------- phase 2c: suffix-scan hist2 -> bin2 ----------
__global__ __launch_bounds__(1024) void scan2_kernel(const unsigned int* __restrict__ ghist2,
                                                     int* __restrict__ meta) {
    const int b = blockIdx.x, tid = threadIdx.x;
    const unsigned need2 = (unsigned)meta[b * 4 + 1];
    __shared__ unsigned int h[2048];
    const int i0 = tid, i1 = tid + 1024;
    h[i0] = ghist2[b * 2048 + i0];
    h[i1] = ghist2[b * 2048 + i1];
    __syncthreads();
    for (int off = 1; off < 2048; off <<= 1) {
        unsigned a0 = (i0 + off < 2048) ? h[i0 + off] : 0u;
        unsigned a1 = (i1 + off < 2048) ? h[i1 + off] : 0u;
        __syncthreads();
        h[i0] += a0; h[i1] += a1;
        __syncthreads();
    }
    if (h[i0] >= need2 && (i0 == 2047 || h[i0 + 1] < need2)) meta[b * 4 + 2] = i0;
    if (h[i1] >= need2 && (i1 == 2047 || h[i1 + 1] < need2)) meta[b * 4 + 2] = i1;
}

// ---------- phase 2d: chip-parallel candidate collect (22-bit prefix >= pfx) ----------
__global__ __launch_bounds__(256) void collect_kernel(const double* __restrict__ scores,
                                                      const int* __restrict__ meta,
                                                      unsigned long long* __restrict__ ckey,
                                                      int* __restrict__ cidx,
                                                      unsigned int* __restrict__ ccnt) {
    const int b = blockIdx.x / SB;
    const int s = blockIdx.x % SB;
    const unsigned long long pfx =
        ((unsigned long long)meta[b * 4 + 0] << 11) | (unsigned long long)meta[b * 4 + 2];
    const double* sc = scores + (long)b * NN;
    for (int i = s * 256 + threadIdx.x; i < NN / 2; i += SB * 256) {
        double2 v = ((const double2*)sc)[i];
        unsigned long long k0 = key64(v.x), k1 = key64(v.y);
        if ((k0 >> 42) >= pfx) {
            unsigned p = atomicAdd(&ccnt[b], 1u);
            if (p < (unsigned)CAPA) { ckey[b * CAPA + p] = k0; cidx[b * CAPA + p] = 2 * i; }
        }
        if ((k1 >> 42) >= pfx) {
            unsigned p = atomicAdd(&ccnt[b], 1u);
            if (p < (unsigned)CAPA) { ckey[b * CAPA + p] = k1; cidx[b * CAPA + p] = 2 * i + 1; }
        }
    }
}

// ---------- phase 2e: parallel O(M^2) rank (order-invariant exact comparator) ----------
__global__ __launch_bounds__(256) void rank_kernel(const unsigned long long* __restrict__ ckey,
                                                   const int* __restrict__ cidx,
                                                   const unsigned int* __restrict__ ccnt,
                                                   int* __restrict__ topk_idx,
                                                   float* __restrict__ gate) {
    const int b  = blockIdx.x >> 4;       // RBLK=16 blocks per batch
    const int sl = blockIdx.x & (RBLK - 1);
    const unsigned cm = ccnt[b];
    const int M  = (int)(cm < (unsigned)CAPA ? cm : (unsigned)CAPA);
    const int r0 = sl * 256;
    if (r0 >= M) return;

    __shared__ unsigned long long k_s[CAPA];
    __shared__ int i_s[CAPA];

    const unsigned long long* kb = ckey + b * CAPA;
    const int* ib = cidx + b * CAPA;
    for (int i = threadIdx.x; i < M; i += 256) { k_s[i] = kb[i]; i_s[i] = ib[i]; }
    __syncthreads();

    const int r = r0 + threadIdx.x;
    if (r < M) {
        const unsigned long long kr = k_s[r];
        const int ir = i_s[r];
        int rank = 0;
        for (int j = 0; j < M; ++j) {
            const unsigned long long kj = k_s[j];
            rank += (kj > kr) || (kj == kr && i_s[j] < ir);
        }
        if (rank < KK) {
            topk_idx[b * KK + rank] = ir;
            gate[b * KK + rank]     = tanhf((float)key_to_double(kr));
        }
    }
}

// ---------- phase 3: out[b,f,k] = emb[b, idx[b,k], f] * gate[b,k] ----------
__global__ __launch_bounds__(256) void gather_kernel(const float* __restrict__ emb,
                                                     const int* __restrict__ topk_idx,
                                                     const float* __restrict__ gate,
                                                     float* __restrict__ out) {
    const int b  = blockIdx.x >> 5;
    const int kt = blockIdx.x & 31;
    const int k0 = kt * 32;
    const int tid = threadIdx.x;

    __shared__ float tile[32][FF + 4];
    __shared__ int   s_idx[32];
    __shared__ float s_gate[32];

    if (tid < 32) {
        s_idx[tid]  = topk_idx[b * KK + k0 + tid];
        s_gate[tid] = gate[b * KK + k0 + tid];
    }
    __syncthreads();

    const int g = tid >> 6, lane = tid & 63;
    #pragma unroll
    for (int i = 0; i < 8; i++) {
        int kl = i * 4 + g;
        int row = s_idx[kl];
        float gt = s_gate[kl];
        float4 v = ((const float4*)(emb + ((long)b * NN + row) * FF))[lane];
        float* t = &tile[kl][lane * 4];
        t[0] = v.x * gt; t[1] = v.y * gt; t[2] = v.z * gt; t[3] = v.w * gt;
    }
    __syncthreads();

    const long outbase = ((long)b * FF) * KK + k0;
    #pragma unroll
    for (int c = 0; c < 32; c++) {
        int linear = c * 256 + tid;
        int f = linear >> 5;
        int k = linear & 31;
        out[outbase + (long)f * KK + k] = tile[k][f];
    }
}

extern "C" void kernel_launch(void* const* d_in, const int* in_sizes, int n_in,
                              void* d_out, int out_size, void* d_ws, size_t ws_size,
                              hipStream_t stream) {
    const float* emb    = (const float*)d_in[0];  // [B, N, F] fp32
    const float* mask   = (const float*)d_in[1];  // [B, N] fp32
    const float* scorer = (const float*)d_in[2];  // [F, 1] fp32
    float* out = (float*)d_out;                   // [B, F, K] fp32

    char* wsb = (char*)d_ws;
    double*             scores  = (double*)wsb;                                   // 3.2 MB
    unsigned int*       ghist   = (unsigned int*)(wsb + sizeof(double) * BB * NN);          // B*2048
    unsigned int*       ghist2  = ghist + BB * 2048;                                        // B*2048
    unsigned int*       ccnt    = ghist2 + BB * 2048;                                       // B
    int*                meta    = (int*)(ccnt + BB);                                        // B*4
    int*                topkidx = meta + BB * 4;                                            // B*K
    float*              gatep   = (float*)(topkidx + BB * KK);                              // B*K
    unsigned long long* ckey    = (unsigned long long*)((char*)gatep + sizeof(float) * BB * KK);
    int*                cidx    = (int*)((char*)ckey + sizeof(unsigned long long) * BB * CAPA);

    // zero hist1 + hist2 + ccnt in one shot (they are contiguous)
    zero_kernel<<<(BB * 2048 * 2 + BB + 1023) / 1024, 1024, 0, stream>>>(ghist, BB * 2048 * 2 + BB);
    score_kernel<<<BB * NCHUNK, 256, 0, stream>>>(emb, mask, scorer, scores, ghist);
    scan1_kernel<<<BB, 1024, 0, stream>>>(ghist, meta);
    hist2_kernel<<<BB * SB, 256, 0, stream>>>(scores, meta, ghist2);
    scan2_kernel<<<BB, 1024, 0, stream>>>(ghist2, meta);
    collect_kernel<<<BB * SB, 256, 0, stream>>>(scores, meta, ckey, cidx, ccnt);
    rank_kernel<<<BB * RBLK, 256, 0, stream>>>(ckey, cidx, ccnt, topkidx, gatep);
    gather_kernel<<<BB * 32, 256, 0, stream>>>(emb, topkidx, gatep, out);
}